// Round 1
// baseline (346.702 us; speedup 1.0000x reference)
//
#include <hip/hip_runtime.h>
#include <hip/hip_bf16.h>
#include <math.h>

using bf16 = __hip_bfloat16;
typedef __attribute__((ext_vector_type(8))) __bf16 bf16x8;
typedef __attribute__((ext_vector_type(4))) float f32x4;

static __device__ __forceinline__ void gload16(const bf16* g, bf16* l) {
  __builtin_amdgcn_global_load_lds((const __attribute__((address_space(1))) void*)g,
                                   (__attribute__((address_space(3))) void*)l, 16, 0, 0);
}

// ---------------------------------------------------------------------------
// f32 -> bf16 conversion (vectorized 4/thread)
// ---------------------------------------------------------------------------
__global__ __launch_bounds__(256) void cvt_f32_bf16(const float* __restrict__ in,
                                                    bf16* __restrict__ out, int n4) {
  const int i = blockIdx.x * 256 + threadIdx.x;
  if (i >= n4) return;
  const float4 v = reinterpret_cast<const float4*>(in)[i];
  union { bf16 h[4]; short4 s; } u;
  u.h[0] = __float2bfloat16(v.x);
  u.h[1] = __float2bfloat16(v.y);
  u.h[2] = __float2bfloat16(v.z);
  u.h[3] = __float2bfloat16(v.w);
  *reinterpret_cast<short4*>(out + 4 * (size_t)i) = u.s;
}

// ---------------------------------------------------------------------------
// NT GEMM: C[M,N] = A[M,K] * B[N,K]^T (+bias). m97 structure:
// 128x128 tile, BK=32, 4 waves (each 64x64 = 4x4 frags of 16x16),
// global_load_lds width-16 staging, mfma_f32_16x16x32_bf16.
// CAUSAL: skip blocks fully above the diagonal (scores GEMM).
// KTRUNC: stop K loop at rowBase+128 (PV GEMM; A is zero above diagonal).
// ---------------------------------------------------------------------------
template<bool BIAS, bool F32OUT, bool CAUSAL, bool KTRUNC>
__global__ __launch_bounds__(256, 2) void gemm_nt(
    const bf16* __restrict__ A, const bf16* __restrict__ B, void* __restrict__ Cv,
    const float* __restrict__ bias, int K, int lda, int ldb, int ldc,
    long sA, long sB, long sC)
{
  if (CAUSAL && blockIdx.x > blockIdx.y) return;
  A += (long)blockIdx.z * sA;
  B += (long)blockIdx.z * sB;
  const int rowBase = blockIdx.y * 128;
  const int colBase = blockIdx.x * 128;
  const int tid  = threadIdx.x;
  const int lane = tid & 63;
  const int wid  = tid >> 6;
  const int wR = (wid >> 1) * 64;
  const int wC = (wid & 1) * 64;

  __shared__ alignas(16) bf16 lsA[128 * 32];
  __shared__ alignas(16) bf16 lsB[128 * 32];

  f32x4 acc[4][4] = {};

  const int kEnd = KTRUNC ? (rowBase + 128) : K;
  const int rt = tid >> 2;          // staging row 0..63
  const int c8 = (tid & 3) * 8;     // staging k-offset (8 bf16 = 16B)
  const bf16* gA = A + (size_t)(rowBase + rt) * lda + c8;
  const bf16* gB = B + (size_t)(colBase + rt) * ldb + c8;
  const int lr = lane >> 4;         // k-chunk for frags / row group for C
  const int lc = lane & 15;         // row (A) / col (B,C) within 16

  for (int k0 = 0; k0 < kEnd; k0 += 32) {
    gload16(gA + k0,                    &lsA[rt * 32 + c8]);
    gload16(gA + (size_t)64 * lda + k0, &lsA[(rt + 64) * 32 + c8]);
    gload16(gB + k0,                    &lsB[rt * 32 + c8]);
    gload16(gB + (size_t)64 * ldb + k0, &lsB[(rt + 64) * 32 + c8]);
    __syncthreads();   // compiler drains vmcnt before barrier

    bf16x8 af[4], bf_[4];
#pragma unroll
    for (int m = 0; m < 4; ++m)
      af[m] = *reinterpret_cast<const bf16x8*>(&lsA[(wR + m * 16 + lc) * 32 + lr * 8]);
#pragma unroll
    for (int n = 0; n < 4; ++n)
      bf_[n] = *reinterpret_cast<const bf16x8*>(&lsB[(wC + n * 16 + lc) * 32 + lr * 8]);

#pragma unroll
    for (int m = 0; m < 4; ++m)
#pragma unroll
      for (int n = 0; n < 4; ++n)
        acc[m][n] = __builtin_amdgcn_mfma_f32_16x16x32_bf16(af[m], bf_[n], acc[m][n], 0, 0, 0);
    __syncthreads();
  }

  const long cbase = (long)blockIdx.z * sC;
#pragma unroll
  for (int m = 0; m < 4; ++m) {
    const int row0 = rowBase + wR + m * 16 + lr * 4;
#pragma unroll
    for (int n = 0; n < 4; ++n) {
      const int col = colBase + wC + n * 16 + lc;
      const float bv = BIAS ? bias[col] : 0.f;
#pragma unroll
      for (int j = 0; j < 4; ++j) {
        const float v = acc[m][n][j] + bv;
        const long idx = cbase + (long)(row0 + j) * ldc + col;
        if (F32OUT) reinterpret_cast<float*>(Cv)[idx] = v;
        else        reinterpret_cast<bf16*>(Cv)[idx] = __float2bfloat16(v);
      }
    }
  }
}

// ---------------------------------------------------------------------------
// RoPE on first 128 dims, in-place on bf16 [4096, 2048]; pos = row % 2048
// ---------------------------------------------------------------------------
__global__ __launch_bounds__(256) void rope_bf16(bf16* __restrict__ X) {
  const int idx = blockIdx.x * 256 + threadIdx.x;  // 4096*64 pairs
  const int row = idx >> 6;
  const int i   = idx & 63;
  const int t   = row & 2047;
  // inv_freq = 10000^(-i/64) = 2^(-i*log2(10000)/64)
  const float ang = (float)t * exp2f((float)i * -0.20762050593046f);
  float sn, cs;
  sincosf(ang, &sn, &cs);
  bf16* p = X + ((long)row << 11) + 2 * i;
  const float x1 = __bfloat162float(p[0]);
  const float x2 = __bfloat162float(p[1]);
  p[0] = __float2bfloat16(x1 * cs - x2 * sn);
  p[1] = __float2bfloat16(x2 * cs + x1 * sn);
}

// ---------------------------------------------------------------------------
// Causal row softmax: reads f32 scores row (s<=t), writes bf16 A row
// (full 2048 cols, zeros above diagonal), scale 1/sqrt(128), x2 factor.
// A overlays the S buffer (row stride 4096 bf16 elems). Safe in-place:
// all reads happen before writes (barriers between phases).
// ---------------------------------------------------------------------------
__global__ __launch_bounds__(256) void softmax_causal(
    const float* __restrict__ S, bf16* __restrict__ Aout, long sS, long sA) {
  const int t = blockIdx.x;
  const int b = blockIdx.y;
  const float* row = S + (long)b * sS + (long)t * 2048;
  bf16* orow = Aout + (long)b * sA + (long)t * 4096;
  const int L = t + 1;
  __shared__ float e[2048];
  __shared__ float red[4];
  const float scale = 0.0883883476483184f;  // 1/sqrt(128)
  const int lane = threadIdx.x & 63, wd = threadIdx.x >> 6;

  float mx = -INFINITY;
  for (int s = threadIdx.x; s < L; s += 256) {
    const float v = row[s] * scale;
    e[s] = v;
    mx = fmaxf(mx, v);
  }
#pragma unroll
  for (int off = 1; off < 64; off <<= 1) mx = fmaxf(mx, __shfl_xor(mx, off));
  if (lane == 0) red[wd] = mx;
  __syncthreads();
  mx = fmaxf(fmaxf(red[0], red[1]), fmaxf(red[2], red[3]));
  __syncthreads();

  float sum = 0.f;
  for (int s = threadIdx.x; s < L; s += 256) {
    const float v = expf(e[s] - mx);
    e[s] = v;
    sum += v;
  }
#pragma unroll
  for (int off = 1; off < 64; off <<= 1) sum += __shfl_xor(sum, off);
  if (lane == 0) red[wd] = sum;
  __syncthreads();
  sum = red[0] + red[1] + red[2] + red[3];
  const float f = 2.f / sum;
  for (int s = threadIdx.x; s < 2048; s += 256) {
    const float v = (s < L) ? e[s] * f : 0.f;
    orow[s] = __float2bfloat16(v);
  }
}

// ---------------------------------------------------------------------------
// bf16 transpose per batch: VT[b][d][s] = V[b][s][d]   (2048x2048 each)
// ---------------------------------------------------------------------------
__global__ __launch_bounds__(256) void transpose_bf16(
    const bf16* __restrict__ V, bf16* __restrict__ VT) {
  __shared__ bf16 tile[32][33];
  const long b = blockIdx.z;
  const int s0 = blockIdx.y * 32, d0 = blockIdx.x * 32;
  const int tx = threadIdx.x;  // 0..31
  const int ty = threadIdx.y;  // 0..7
  for (int i = ty; i < 32; i += 8)
    tile[i][tx] = V[(b * 2048 + s0 + i) * 2048 + d0 + tx];
  __syncthreads();
  for (int i = ty; i < 32; i += 8)
    VT[(b * 2048 + d0 + i) * 2048 + s0 + tx] = tile[tx][i];
}

// ---------------------------------------------------------------------------
extern "C" void kernel_launch(void* const* d_in, const int* in_sizes, int n_in,
                              void* d_out, int out_size, void* d_ws, size_t ws_size,
                              hipStream_t stream) {
  (void)in_sizes; (void)n_in; (void)out_size; (void)ws_size;
  const float* lat = (const float*)d_in[0];
  const float* Wq  = (const float*)d_in[1];
  const float* bq  = (const float*)d_in[2];
  const float* Wk  = (const float*)d_in[3];
  const float* bk  = (const float*)d_in[4];
  const float* Wv  = (const float*)d_in[5];
  const float* bv  = (const float*)d_in[6];
  const float* Wfc = (const float*)d_in[7];
  const float* bfc = (const float*)d_in[8];
  float* out = (float*)d_out;

  constexpr long T = 2048, D = 2048, MT = 4096;  // B=2
  char* w = (char*)d_ws;
  bf16* latb = (bf16*)w;  w += MT * D * 2;        // 16MB (later overlaid by O)
  bf16* wqb  = (bf16*)w;  w += D * D * 2;         // 8MB
  bf16* wkb  = (bf16*)w;  w += D * D * 2;
  bf16* wvb  = (bf16*)w;  w += D * D * 2;
  bf16* wfb  = (bf16*)w;  w += D * D * 2;
  bf16* Qb   = (bf16*)w;  w += MT * D * 2;        // 16MB
  bf16* Kb   = (bf16*)w;  w += MT * D * 2;
  bf16* Vb   = (bf16*)w;  w += MT * D * 2;
  bf16* VTb  = (bf16*)w;  w += MT * D * 2;
  float* S   = (float*)w; w += 2 * T * T * 4;     // 32MB
  bf16* Ab   = (bf16*)S;                          // overlay (row stride 4096)
  bf16* Ob   = latb;                              // overlay

  // 1) convert to bf16
  cvt_f32_bf16<<<8192, 256, 0, stream>>>(lat, latb, (int)(MT * D / 4));
  cvt_f32_bf16<<<4096, 256, 0, stream>>>(Wq, wqb, (int)(D * D / 4));
  cvt_f32_bf16<<<4096, 256, 0, stream>>>(Wk, wkb, (int)(D * D / 4));
  cvt_f32_bf16<<<4096, 256, 0, stream>>>(Wv, wvb, (int)(D * D / 4));
  cvt_f32_bf16<<<4096, 256, 0, stream>>>(Wfc, wfb, (int)(D * D / 4));

  // 2) Q/K/V projections (+bias), bf16 out
  dim3 g1(16, 32, 1);
  gemm_nt<true,false,false,false><<<g1, 256, 0, stream>>>(latb, wqb, Qb, bq, 2048, 2048, 2048, 2048, 0, 0, 0);
  gemm_nt<true,false,false,false><<<g1, 256, 0, stream>>>(latb, wkb, Kb, bk, 2048, 2048, 2048, 2048, 0, 0, 0);
  gemm_nt<true,false,false,false><<<g1, 256, 0, stream>>>(latb, wvb, Vb, bv, 2048, 2048, 2048, 2048, 0, 0, 0);

  // 3) RoPE on Q, K (first 128 dims)
  rope_bf16<<<1024, 256, 0, stream>>>(Qb);
  rope_bf16<<<1024, 256, 0, stream>>>(Kb);

  // 4) scores S = Q K^T per batch (causal block skip), f32 out
  dim3 g2(16, 16, 2);
  gemm_nt<false,true,true,false><<<g2, 256, 0, stream>>>(Qb, Kb, S, nullptr,
      2048, 2048, 2048, 2048, T * D, T * D, T * T);

  // 5) softmax rows -> bf16 A (overlay on S)
  softmax_causal<<<dim3(2048, 2), 256, 0, stream>>>(S, Ab, T * T, T * 2 * T);

  // 6) V transpose per batch
  transpose_bf16<<<dim3(64, 64, 2), dim3(32, 8), 0, stream>>>(Vb, VTb);

  // 7) O = A V (K-loop truncated at diagonal), bf16 out (overlay on latb)
  gemm_nt<false,false,false,true><<<g2, 256, 0, stream>>>(Ab, VTb, Ob, nullptr,
      2048, 4096, 2048, 2048, T * 2 * T, D * T, T * D);

  // 8) out = O Wfc^T + bfc, f32 to d_out
  gemm_nt<true,true,false,false><<<g1, 256, 0, stream>>>(Ob, wfb, out, bfc,
      2048, 2048, 2048, 2048, 0, 0, 0);
}

// Round 2
// 313.483 us; speedup vs baseline: 1.1060x; 1.1060x over previous
//
#include <hip/hip_runtime.h>
#include <hip/hip_bf16.h>
#include <math.h>

using bf16 = __hip_bfloat16;
typedef __attribute__((ext_vector_type(8))) __bf16 bf16x8;
typedef __attribute__((ext_vector_type(4))) float f32x4;

static __device__ __forceinline__ void gload16(const bf16* g, bf16* l) {
  __builtin_amdgcn_global_load_lds((const __attribute__((address_space(1))) void*)g,
                                   (__attribute__((address_space(3))) void*)l, 16, 0, 0);
}

struct POff { long a[4]; long b[4]; long c[4]; const float* bias[4]; };
struct CvtP { const float* s[5]; bf16* d[5]; int n4[5]; };

// ---------------------------------------------------------------------------
// fused f32 -> bf16 conversion for 5 tensors (y selects tensor)
// ---------------------------------------------------------------------------
__global__ __launch_bounds__(256) void cvt_f32_bf16(CvtP p) {
  const int y = blockIdx.y;
  const int i = blockIdx.x * 256 + threadIdx.x;
  if (i >= p.n4[y]) return;
  const float4 v = reinterpret_cast<const float4*>(p.s[y])[i];
  union { bf16 h[4]; short4 s4; } u;
  u.h[0] = __float2bfloat16(v.x);
  u.h[1] = __float2bfloat16(v.y);
  u.h[2] = __float2bfloat16(v.z);
  u.h[3] = __float2bfloat16(v.w);
  *reinterpret_cast<short4*>(p.d[y] + 4 * (size_t)i) = u.s4;
}

// ---------------------------------------------------------------------------
// NT GEMM: C[M,N] = A[M,K] * B[N,K]^T (+bias), m97 structure + LDS swizzle.
// 128x128 tile, BK=32, 4 waves. Swizzle: data k-chunk c of row r is stored
// at chunk-slot c ^ ((r>>1)&3) (16B chunks). Linear global_load_lds dest +
// pre-swizzled global source + swizzled ds_read (2-way max = conflict-free).
// CAUSAL: skip blocks above diagonal. KTRUNC: kEnd=rowBase+128, heavy-first.
// Per-z byte offsets/bias come from POff (a,b,c are byte offsets).
// ---------------------------------------------------------------------------
template<bool BIAS, bool F32OUT, bool CAUSAL, bool KTRUNC>
__global__ __launch_bounds__(256, 4) void gemm_nt(
    const bf16* __restrict__ A, const bf16* __restrict__ B, char* __restrict__ Cv,
    POff P, int K, int lda, int ldb, int ldc)
{
  if (CAUSAL && blockIdx.x > blockIdx.y) return;
  const int z = blockIdx.z;
  A = (const bf16*)((const char*)A + P.a[z]);
  B = (const bf16*)((const char*)B + P.b[z]);
  char* C = Cv + P.c[z];
  const int by = KTRUNC ? (gridDim.y - 1 - blockIdx.y) : blockIdx.y;
  const int rowBase = by * 128;
  const int colBase = blockIdx.x * 128;
  const int tid  = threadIdx.x;
  const int lane = tid & 63;
  const int wid  = tid >> 6;
  const int wR = (wid >> 1) * 64;
  const int wC = (wid & 1) * 64;

  __shared__ alignas(16) bf16 lsA[128 * 32];
  __shared__ alignas(16) bf16 lsB[128 * 32];

  f32x4 acc[4][4] = {};

  const int kEnd = KTRUNC ? (rowBase + 128) : K;
  const int rt = tid >> 2;                         // staging row 0..63
  const int cs = tid & 3;                          // chunk slot in LDS
  const int srcOff = (cs ^ ((rt >> 1) & 3)) * 8;   // pre-swizzled source chunk
  const bf16* gA = A + (size_t)(rowBase + rt) * lda + srcOff;
  const bf16* gB = B + (size_t)(colBase + rt) * ldb + srcOff;
  const int lr = lane >> 4;                        // k-chunk for frags
  const int lc = lane & 15;                        // row (A) / col (B,C)
  const int kb = (lr ^ ((lc >> 1) & 3)) * 8;       // swizzled read chunk

  for (int k0 = 0; k0 < kEnd; k0 += 32) {
    gload16(gA + k0,                    &lsA[tid * 8]);
    gload16(gA + (size_t)64 * lda + k0, &lsA[2048 + tid * 8]);
    gload16(gB + k0,                    &lsB[tid * 8]);
    gload16(gB + (size_t)64 * ldb + k0, &lsB[2048 + tid * 8]);
    __syncthreads();

    bf16x8 af[4], bf_[4];
#pragma unroll
    for (int m = 0; m < 4; ++m)
      af[m] = *reinterpret_cast<const bf16x8*>(&lsA[(wR + m * 16 + lc) * 32 + kb]);
#pragma unroll
    for (int n = 0; n < 4; ++n)
      bf_[n] = *reinterpret_cast<const bf16x8*>(&lsB[(wC + n * 16 + lc) * 32 + kb]);

#pragma unroll
    for (int m = 0; m < 4; ++m)
#pragma unroll
      for (int n = 0; n < 4; ++n)
        acc[m][n] = __builtin_amdgcn_mfma_f32_16x16x32_bf16(af[m], bf_[n], acc[m][n], 0, 0, 0);
    __syncthreads();
  }

  const float* bias = P.bias[z];
#pragma unroll
  for (int m = 0; m < 4; ++m) {
    const int row0 = rowBase + wR + m * 16 + lr * 4;
#pragma unroll
    for (int n = 0; n < 4; ++n) {
      const int col = colBase + wC + n * 16 + lc;
      const float bv = BIAS ? bias[col] : 0.f;
#pragma unroll
      for (int j = 0; j < 4; ++j) {
        const float v = acc[m][n][j] + bv;
        const long idx = (long)(row0 + j) * ldc + col;
        if (F32OUT) reinterpret_cast<float*>(C)[idx] = v;
        else        reinterpret_cast<bf16*>(C)[idx] = __float2bfloat16(v);
      }
    }
  }
}

// ---------------------------------------------------------------------------
// RoPE on first 128 dims, in-place on bf16 [8192, 2048] (Q then K); pos=row%2048
// ---------------------------------------------------------------------------
__global__ __launch_bounds__(256) void rope_bf16(bf16* __restrict__ X) {
  const int idx = blockIdx.x * 256 + threadIdx.x;  // 8192*64 pairs
  const int row = idx >> 6;
  const int i   = idx & 63;
  const int t   = row & 2047;
  const float ang = (float)t * exp2f((float)i * -0.20762050593046f);
  float sn, cs;
  sincosf(ang, &sn, &cs);
  bf16* p = X + ((long)row << 11) + 2 * i;
  const float x1 = __bfloat162float(p[0]);
  const float x2 = __bfloat162float(p[1]);
  p[0] = __float2bfloat16(x1 * cs - x2 * sn);
  p[1] = __float2bfloat16(x2 * cs + x1 * sn);
}

// ---------------------------------------------------------------------------
// Causal row softmax over split-K partial scores: row = Sa[t]+Sb[t].
// Writes bf16 A row (stride 4096, zeros above diagonal), scale 1/sqrt(128), x2.
// A overlays Sa's buffer region (in-place per row; reads precede writes).
// ---------------------------------------------------------------------------
__global__ __launch_bounds__(256) void softmax_causal(
    const float* __restrict__ S0, const float* __restrict__ S1,
    const float* __restrict__ S2, const float* __restrict__ S3,
    bf16* __restrict__ A0, bf16* __restrict__ A1) {
  const int t = blockIdx.x;
  const int b = blockIdx.y;
  const float* ra = (b ? S2 : S0) + (long)t * 2048;
  const float* rb = (b ? S3 : S1) + (long)t * 2048;
  bf16* orow = (b ? A1 : A0) + (long)t * 4096;
  const int L = t + 1;
  __shared__ float e[2048];
  __shared__ float red[4];
  const float scale = 0.0883883476483184f;  // 1/sqrt(128)
  const int lane = threadIdx.x & 63, wd = threadIdx.x >> 6;

  float mx = -INFINITY;
  for (int s = threadIdx.x; s < L; s += 256) {
    const float v = (ra[s] + rb[s]) * scale;
    e[s] = v;
    mx = fmaxf(mx, v);
  }
#pragma unroll
  for (int off = 1; off < 64; off <<= 1) mx = fmaxf(mx, __shfl_xor(mx, off));
  if (lane == 0) red[wd] = mx;
  __syncthreads();
  mx = fmaxf(fmaxf(red[0], red[1]), fmaxf(red[2], red[3]));
  __syncthreads();

  float sum = 0.f;
  for (int s = threadIdx.x; s < L; s += 256) {
    const float v = expf(e[s] - mx);
    e[s] = v;
    sum += v;
  }
#pragma unroll
  for (int off = 1; off < 64; off <<= 1) sum += __shfl_xor(sum, off);
  if (lane == 0) red[wd] = sum;
  __syncthreads();
  sum = red[0] + red[1] + red[2] + red[3];
  const float f = 2.f / sum;
  for (int s = threadIdx.x; s < 2048; s += 256) {
    const float v = (s < L) ? e[s] * f : 0.f;
    orow[s] = __float2bfloat16(v);
  }
}

// ---------------------------------------------------------------------------
// bf16 transpose per batch: VT[b][d][s] = V[b][s][d]   (2048x2048 each)
// ---------------------------------------------------------------------------
__global__ __launch_bounds__(256) void transpose_bf16(
    const bf16* __restrict__ V, bf16* __restrict__ VT) {
  __shared__ bf16 tile[32][33];
  const long b = blockIdx.z;
  const int s0 = blockIdx.y * 32, d0 = blockIdx.x * 32;
  const int tx = threadIdx.x;  // 0..31
  const int ty = threadIdx.y;  // 0..7
  for (int i = ty; i < 32; i += 8)
    tile[i][tx] = V[(b * 2048 + s0 + i) * 2048 + d0 + tx];
  __syncthreads();
  for (int i = ty; i < 32; i += 8)
    VT[(b * 2048 + d0 + i) * 2048 + s0 + tx] = tile[tx][i];
}

// ---------------------------------------------------------------------------
extern "C" void kernel_launch(void* const* d_in, const int* in_sizes, int n_in,
                              void* d_out, int out_size, void* d_ws, size_t ws_size,
                              hipStream_t stream) {
  (void)in_sizes; (void)n_in; (void)out_size; (void)ws_size;
  const float* lat = (const float*)d_in[0];
  const float* Wq  = (const float*)d_in[1];
  const float* bq  = (const float*)d_in[2];
  const float* Wk  = (const float*)d_in[3];
  const float* bk  = (const float*)d_in[4];
  const float* Wv  = (const float*)d_in[5];
  const float* bv  = (const float*)d_in[6];
  const float* Wfc = (const float*)d_in[7];
  const float* bfc = (const float*)d_in[8];
  float* out = (float*)d_out;

  constexpr long T = 2048, D = 2048, MT = 4096;  // B=2
  constexpr long TTB = T * T * 4;                // bytes per f32 score buffer
  char* w = (char*)d_ws;
  bf16* latb = (bf16*)w;  w += MT * D * 2;       // 16MB (later overlaid by O)
  bf16* wqb  = (bf16*)w;  w += D * D * 2;        // weights contiguous (wq,wk,wv,wfc)
  bf16* wkb  = (bf16*)w;  w += D * D * 2;
  bf16* wvb  = (bf16*)w;  w += D * D * 2;
  bf16* wfb  = (bf16*)w;  w += D * D * 2;
  bf16* Qb   = (bf16*)w;  w += MT * D * 2;       // Q,K,V contiguous
  bf16* Kb   = (bf16*)w;  w += MT * D * 2;
  bf16* Vb   = (bf16*)w;  w += MT * D * 2;
  bf16* VTb  = (bf16*)w;  w += MT * D * 2;
  float* S0  = (float*)w; w += TTB;              // batch0 k-half partials
  float* S1  = (float*)w; w += TTB;
  float* S2  = (float*)d_out;                    // batch1 partials live in d_out
  float* S3  = (float*)((char*)d_out + TTB);
  bf16* A0   = (bf16*)S0;                        // A overlays (row stride 4096)
  bf16* A1   = (bf16*)S3;
  bf16* Ob   = latb;                             // O overlays latb

  // 1) convert everything to bf16 (one dispatch)
  CvtP cp;
  cp.s[0] = lat; cp.d[0] = latb; cp.n4[0] = (int)(MT * D / 4);
  cp.s[1] = Wq;  cp.d[1] = wqb;  cp.n4[1] = (int)(D * D / 4);
  cp.s[2] = Wk;  cp.d[2] = wkb;  cp.n4[2] = (int)(D * D / 4);
  cp.s[3] = Wv;  cp.d[3] = wvb;  cp.n4[3] = (int)(D * D / 4);
  cp.s[4] = Wfc; cp.d[4] = wfb;  cp.n4[4] = (int)(D * D / 4);
  cvt_f32_bf16<<<dim3(8192, 5), 256, 0, stream>>>(cp);

  // 2) Q/K/V projections fused (+bias), bf16 out
  POff pq = {};
  for (int z = 0; z < 3; ++z) {
    pq.a[z] = 0;
    pq.b[z] = (long)z * D * D * 2;
    pq.c[z] = (long)z * MT * D * 2;
  }
  pq.bias[0] = bq; pq.bias[1] = bk; pq.bias[2] = bv;
  gemm_nt<true,false,false,false><<<dim3(16, 32, 3), 256, 0, stream>>>(
      latb, wqb, (char*)Qb, pq, 2048, 2048, 2048, 2048);

  // 3) RoPE on Q and K (contiguous: 8192 rows)
  rope_bf16<<<2048, 256, 0, stream>>>(Qb);

  // 4) scores split-K: z = batch*2 + khalf, K=1024 each, causal skip, f32
  POff ps = {};
  for (int z = 0; z < 4; ++z) {
    ps.a[z] = (long)(z >> 1) * T * D * 2 + (long)(z & 1) * 1024 * 2;
    ps.b[z] = ps.a[z];
  }
  ps.c[0] = 0;
  ps.c[1] = TTB;
  ps.c[2] = (char*)S2 - (char*)S0;
  ps.c[3] = (char*)S3 - (char*)S0;
  gemm_nt<false,true,true,false><<<dim3(16, 16, 4), 256, 0, stream>>>(
      Qb, Kb, (char*)S0, ps, 1024, 2048, 2048, 2048);

  // 5) softmax rows (sum the two k-half partials) -> bf16 A
  softmax_causal<<<dim3(2048, 2), 256, 0, stream>>>(S0, S1, S2, S3, A0, A1);

  // 6) V transpose per batch
  transpose_bf16<<<dim3(64, 64, 2), dim3(32, 8), 0, stream>>>(Vb, VTb);

  // 7) O = A V (K truncated at diagonal, heaviest-first), bf16 out
  POff pv = {};
  pv.a[0] = 0; pv.a[1] = (char*)A1 - (char*)A0;
  pv.b[0] = 0; pv.b[1] = (long)D * T * 2;
  pv.c[0] = 0; pv.c[1] = (long)T * D * 2;
  gemm_nt<false,false,false,true><<<dim3(16, 16, 2), 256, 0, stream>>>(
      (const bf16*)A0, VTb, (char*)Ob, pv, 2048, 4096, 2048, 2048);

  // 8) out = O Wfc^T + bfc, f32 to d_out
  POff pf = {};
  pf.bias[0] = bfc;
  gemm_nt<true,true,false,false><<<dim3(16, 32, 1), 256, 0, stream>>>(
      Ob, wfb, (char*)out, pf, 2048, 2048, 2048, 2048);
}

// Round 3
// 289.938 us; speedup vs baseline: 1.1958x; 1.0812x over previous
//
#include <hip/hip_runtime.h>
#include <hip/hip_bf16.h>
#include <math.h>

using bf16 = __hip_bfloat16;
typedef __attribute__((ext_vector_type(8))) __bf16 bf16x8;
typedef __attribute__((ext_vector_type(4))) float f32x4;

#define SBAR() asm volatile("s_barrier" ::: "memory")
#define WAITVM(n) asm volatile("s_waitcnt vmcnt(" #n ")" ::: "memory")

static __device__ __forceinline__ void gload16(const bf16* g, bf16* l) {
  __builtin_amdgcn_global_load_lds((const __attribute__((address_space(1))) void*)g,
                                   (__attribute__((address_space(3))) void*)l, 16, 0, 0);
}

struct POff { long a[4]; long b[4]; long c[4]; const float* bias[4]; };
struct CvtP { const float* s[5]; bf16* d[5]; int n4[5]; };

// ---------------------------------------------------------------------------
// fused f32 -> bf16 conversion for 5 tensors (y selects tensor)
// ---------------------------------------------------------------------------
__global__ __launch_bounds__(256) void cvt_f32_bf16(CvtP p) {
  const int y = blockIdx.y;
  const int i = blockIdx.x * 256 + threadIdx.x;
  if (i >= p.n4[y]) return;
  const float4 v = reinterpret_cast<const float4*>(p.s[y])[i];
  union { bf16 h[4]; short4 s4; } u;
  u.h[0] = __float2bfloat16(v.x);
  u.h[1] = __float2bfloat16(v.y);
  u.h[2] = __float2bfloat16(v.z);
  u.h[3] = __float2bfloat16(v.w);
  *reinterpret_cast<short4*>(p.d[y] + 4 * (size_t)i) = u.s4;
}

// ---------------------------------------------------------------------------
// Deep-pipelined NT GEMM: C[M,N] = A[M,K] * B[N,K]^T (+bias).
// BM=256, BN=128, BK=32, 512 thr / 8 waves (4x2), acc[4][4] per wave.
// 4 LDS buffers, stage tile t+3 during tile t (3 gload_lds/thread/tile),
// counted vmcnt(6) steady state (2 tiles in flight), raw s_barrier (no
// compiler vmcnt(0) drains), setprio around the 16-MFMA cluster.
// T2 swizzle: 16B chunk c of row r stored at slot c ^ ((r>>1)&3); linear
// gload_lds dest + pre-swizzled global source + swizzled ds_read.
// CAUSAL: skip blocks with bx > 2*by+1. KTRUNC: kEnd = rowBase+256.
// ---------------------------------------------------------------------------
template<bool BIAS, bool F32OUT, bool CAUSAL, bool KTRUNC>
__global__ __launch_bounds__(512, 2) void gemm_nt(
    const bf16* __restrict__ A, const bf16* __restrict__ B, char* __restrict__ Cv,
    POff P, int K, int lda, int ldb, int ldc)
{
  if (CAUSAL && (int)blockIdx.x > 2 * (int)blockIdx.y + 1) return;
  const int z = blockIdx.z;
  A = (const bf16*)((const char*)A + P.a[z]);
  B = (const bf16*)((const char*)B + P.b[z]);
  char* C = Cv + P.c[z];
  const int by = KTRUNC ? ((int)gridDim.y - 1 - (int)blockIdx.y) : (int)blockIdx.y;
  const int rowBase = by * 256;
  const int colBase = blockIdx.x * 128;
  const int tid  = threadIdx.x;
  const int lane = tid & 63;
  const int wid  = tid >> 6;
  const int wm = wid >> 1;   // 0..3 -> 64-row strip
  const int wn = wid & 1;    // 0..1 -> 64-col strip
  const int kEnd = KTRUNC ? (rowBase + 256) : K;
  const int NT = kEnd >> 5;  // 32-wide K tiles (>= 8 for all our shapes)

  __shared__ alignas(16) bf16 ls[4][12288];  // per buf: A 256x32 | B 128x32

  f32x4 acc[4][4] = {};

  // staging addressing: 512 thr x 16B covers 128 rows x 4 chunks
  const int rt  = tid >> 2;                        // row 0..127
  const int sw8 = ((tid & 3) ^ ((rt >> 1) & 3)) * 8;  // pre-swizzled src chunk
  const bf16* gA0 = A + (size_t)(rowBase + rt) * lda + sw8;
  const bf16* gA1 = gA0 + (size_t)128 * lda;
  const bf16* gB0 = B + (size_t)(colBase + rt) * ldb + sw8;

  // fragment read addressing
  const int lr = lane >> 4, lc = lane & 15;
  const int kb = (lr ^ ((lc >> 1) & 3)) * 8;       // swizzled read chunk

#define STAGE(t) { bf16* d = &ls[(t) & 3][0]; const int ko = (t) * 32; \
    gload16(gA0 + ko, &d[tid * 8]); \
    gload16(gA1 + ko, &d[4096 + tid * 8]); \
    gload16(gB0 + ko, &d[8192 + tid * 8]); }

  STAGE(0); STAGE(1); STAGE(2);

  for (int t = 0; t < NT; ++t) {
    if (t < NT - 2)       WAITVM(6);   // my tile-t loads done; t+1,t+2 in flight
    else if (t == NT - 2) WAITVM(3);
    else                  WAITVM(0);
    SBAR();                            // all waves' tile-t data resident
    const bf16* LA = &ls[t & 3][0];
    const bf16* LB = &ls[t & 3][8192];
    bf16x8 af[4], bfr[4];
#pragma unroll
    for (int m = 0; m < 4; ++m)
      af[m] = *reinterpret_cast<const bf16x8*>(&LA[(wm * 64 + m * 16 + lc) * 32 + kb]);
#pragma unroll
    for (int n = 0; n < 4; ++n)
      bfr[n] = *reinterpret_cast<const bf16x8*>(&LB[(wn * 64 + n * 16 + lc) * 32 + kb]);
    if (t + 3 < NT) STAGE(t + 3);      // writes buf (t+3)&3 != (t)&3; safe
    SBAR();
    __builtin_amdgcn_s_setprio(1);
#pragma unroll
    for (int m = 0; m < 4; ++m)
#pragma unroll
      for (int n = 0; n < 4; ++n)
        acc[m][n] = __builtin_amdgcn_mfma_f32_16x16x32_bf16(af[m], bfr[n], acc[m][n], 0, 0, 0);
    __builtin_amdgcn_s_setprio(0);
  }
#undef STAGE

  const float* bias = P.bias[z];
  const int crow0 = rowBase + wm * 64;
  const int ccol0 = colBase + wn * 64;
#pragma unroll
  for (int m = 0; m < 4; ++m) {
    const int row0 = crow0 + m * 16 + lr * 4;
#pragma unroll
    for (int n = 0; n < 4; ++n) {
      const int col = ccol0 + n * 16 + lc;
      const float bv = BIAS ? bias[col] : 0.f;
#pragma unroll
      for (int j = 0; j < 4; ++j) {
        const float v = acc[m][n][j] + bv;
        const long idx = (long)(row0 + j) * ldc + col;
        if (F32OUT) reinterpret_cast<float*>(C)[idx] = v;
        else        reinterpret_cast<bf16*>(C)[idx] = __float2bfloat16(v);
      }
    }
  }
}

// ---------------------------------------------------------------------------
// RoPE on first 128 dims, in-place on bf16 [8192, 2048] (Q then K); pos=row%2048
// ---------------------------------------------------------------------------
__global__ __launch_bounds__(256) void rope_bf16(bf16* __restrict__ X) {
  const int idx = blockIdx.x * 256 + threadIdx.x;  // 8192*64 pairs
  const int row = idx >> 6;
  const int i   = idx & 63;
  const int t   = row & 2047;
  const float ang = (float)t * exp2f((float)i * -0.20762050593046f);
  float sn, cs;
  sincosf(ang, &sn, &cs);
  bf16* p = X + ((long)row << 11) + 2 * i;
  const float x1 = __bfloat162float(p[0]);
  const float x2 = __bfloat162float(p[1]);
  p[0] = __float2bfloat16(x1 * cs - x2 * sn);
  p[1] = __float2bfloat16(x2 * cs + x1 * sn);
}

// ---------------------------------------------------------------------------
// Causal row softmax over split-K partial scores: row = Sa[t]+Sb[t].
// Writes bf16 A row (stride 4096, zeros above diagonal), scale 1/sqrt(128), x2.
// ---------------------------------------------------------------------------
__global__ __launch_bounds__(256) void softmax_causal(
    const float* __restrict__ S0, const float* __restrict__ S1,
    const float* __restrict__ S2, const float* __restrict__ S3,
    bf16* __restrict__ A0, bf16* __restrict__ A1) {
  const int t = blockIdx.x;
  const int b = blockIdx.y;
  const float* ra = (b ? S2 : S0) + (long)t * 2048;
  const float* rb = (b ? S3 : S1) + (long)t * 2048;
  bf16* orow = (b ? A1 : A0) + (long)t * 4096;
  const int L = t + 1;
  __shared__ float e[2048];
  __shared__ float red[4];
  const float scale = 0.0883883476483184f;  // 1/sqrt(128)
  const int lane = threadIdx.x & 63, wd = threadIdx.x >> 6;

  float mx = -INFINITY;
  for (int s = threadIdx.x; s < L; s += 256) {
    const float v = (ra[s] + rb[s]) * scale;
    e[s] = v;
    mx = fmaxf(mx, v);
  }
#pragma unroll
  for (int off = 1; off < 64; off <<= 1) mx = fmaxf(mx, __shfl_xor(mx, off));
  if (lane == 0) red[wd] = mx;
  __syncthreads();
  mx = fmaxf(fmaxf(red[0], red[1]), fmaxf(red[2], red[3]));
  __syncthreads();

  float sum = 0.f;
  for (int s = threadIdx.x; s < L; s += 256) {
    const float v = expf(e[s] - mx);
    e[s] = v;
    sum += v;
  }
#pragma unroll
  for (int off = 1; off < 64; off <<= 1) sum += __shfl_xor(sum, off);
  if (lane == 0) red[wd] = sum;
  __syncthreads();
  sum = red[0] + red[1] + red[2] + red[3];
  const float f = 2.f / sum;
  for (int s = threadIdx.x; s < 2048; s += 256) {
    const float v = (s < L) ? e[s] * f : 0.f;
    orow[s] = __float2bfloat16(v);
  }
}

// ---------------------------------------------------------------------------
// bf16 transpose per batch: VT[b][d][s] = V[b][s][d]   (2048x2048 each)
// ---------------------------------------------------------------------------
__global__ __launch_bounds__(256) void transpose_bf16(
    const bf16* __restrict__ V, bf16* __restrict__ VT) {
  __shared__ bf16 tile[32][33];
  const long b = blockIdx.z;
  const int s0 = blockIdx.y * 32, d0 = blockIdx.x * 32;
  const int tx = threadIdx.x;  // 0..31
  const int ty = threadIdx.y;  // 0..7
  for (int i = ty; i < 32; i += 8)
    tile[i][tx] = V[(b * 2048 + s0 + i) * 2048 + d0 + tx];
  __syncthreads();
  for (int i = ty; i < 32; i += 8)
    VT[(b * 2048 + d0 + i) * 2048 + s0 + tx] = tile[tx][i];
}

// ---------------------------------------------------------------------------
extern "C" void kernel_launch(void* const* d_in, const int* in_sizes, int n_in,
                              void* d_out, int out_size, void* d_ws, size_t ws_size,
                              hipStream_t stream) {
  (void)in_sizes; (void)n_in; (void)out_size; (void)ws_size;
  const float* lat = (const float*)d_in[0];
  const float* Wq  = (const float*)d_in[1];
  const float* bq  = (const float*)d_in[2];
  const float* Wk  = (const float*)d_in[3];
  const float* bk  = (const float*)d_in[4];
  const float* Wv  = (const float*)d_in[5];
  const float* bv  = (const float*)d_in[6];
  const float* Wfc = (const float*)d_in[7];
  const float* bfc = (const float*)d_in[8];
  float* out = (float*)d_out;

  constexpr long T = 2048, D = 2048, MT = 4096;  // B=2
  constexpr long TTB = T * T * 4;                // bytes per f32 score buffer
  char* w = (char*)d_ws;
  bf16* latb = (bf16*)w;  w += MT * D * 2;       // 16MB (later overlaid by O)
  bf16* wqb  = (bf16*)w;  w += D * D * 2;        // weights contiguous
  bf16* wkb  = (bf16*)w;  w += D * D * 2;
  bf16* wvb  = (bf16*)w;  w += D * D * 2;
  bf16* wfb  = (bf16*)w;  w += D * D * 2;
  bf16* Qb   = (bf16*)w;  w += MT * D * 2;       // Q,K,V contiguous
  bf16* Kb   = (bf16*)w;  w += MT * D * 2;
  bf16* Vb   = (bf16*)w;  w += MT * D * 2;
  bf16* VTb  = (bf16*)w;  w += MT * D * 2;
  float* S0  = (float*)w; w += TTB;              // batch0 k-half partials
  float* S1  = (float*)w; w += TTB;
  float* S2  = (float*)d_out;                    // batch1 partials in d_out
  float* S3  = (float*)((char*)d_out + TTB);
  bf16* A0   = (bf16*)S0;                        // A overlays (row stride 4096)
  bf16* A1   = (bf16*)S3;
  bf16* Ob   = latb;                             // O overlays latb

  // 1) convert everything to bf16 (one dispatch)
  CvtP cp;
  cp.s[0] = lat; cp.d[0] = latb; cp.n4[0] = (int)(MT * D / 4);
  cp.s[1] = Wq;  cp.d[1] = wqb;  cp.n4[1] = (int)(D * D / 4);
  cp.s[2] = Wk;  cp.d[2] = wkb;  cp.n4[2] = (int)(D * D / 4);
  cp.s[3] = Wv;  cp.d[3] = wvb;  cp.n4[3] = (int)(D * D / 4);
  cp.s[4] = Wfc; cp.d[4] = wfb;  cp.n4[4] = (int)(D * D / 4);
  cvt_f32_bf16<<<dim3(8192, 5), 256, 0, stream>>>(cp);

  // 2) Q/K/V projections fused (+bias), bf16 out; 768 blocks = 3 full rounds
  POff pq = {};
  for (int z = 0; z < 3; ++z) {
    pq.a[z] = 0;
    pq.b[z] = (long)z * D * D * 2;
    pq.c[z] = (long)z * MT * D * 2;
  }
  pq.bias[0] = bq; pq.bias[1] = bk; pq.bias[2] = bv;
  gemm_nt<true,false,false,false><<<dim3(16, 16, 3), 512, 0, stream>>>(
      latb, wqb, (char*)Qb, pq, 2048, 2048, 2048, 2048);

  // 3) RoPE on Q and K (contiguous: 8192 rows)
  rope_bf16<<<2048, 256, 0, stream>>>(Qb);

  // 4) scores split-K: z = batch*2 + khalf, K=1024 each, causal skip, f32
  POff ps = {};
  for (int z = 0; z < 4; ++z) {
    ps.a[z] = (long)(z >> 1) * T * D * 2 + (long)(z & 1) * 1024 * 2;
    ps.b[z] = ps.a[z];
  }
  ps.c[0] = 0;
  ps.c[1] = TTB;
  ps.c[2] = (char*)S2 - (char*)S0;
  ps.c[3] = (char*)S3 - (char*)S0;
  gemm_nt<false,true,true,false><<<dim3(16, 8, 4), 512, 0, stream>>>(
      Qb, Kb, (char*)S0, ps, 1024, 2048, 2048, 2048);

  // 5) softmax rows (sum the two k-half partials) -> bf16 A
  softmax_causal<<<dim3(2048, 2), 256, 0, stream>>>(S0, S1, S2, S3, A0, A1);

  // 6) V transpose per batch
  transpose_bf16<<<dim3(64, 64, 2), dim3(32, 8), 0, stream>>>(Vb, VTb);

  // 7) O = A V (K truncated at diagonal), bf16 out; 256 blocks = 1 round
  POff pv = {};
  pv.a[0] = 0; pv.a[1] = (char*)A1 - (char*)A0;
  pv.b[0] = 0; pv.b[1] = (long)D * T * 2;
  pv.c[0] = 0; pv.c[1] = (long)T * D * 2;
  gemm_nt<false,false,false,true><<<dim3(16, 8, 2), 512, 0, stream>>>(
      (const bf16*)A0, VTb, (char*)Ob, pv, 2048, 4096, 2048, 2048);

  // 8) out = O Wfc^T + bfc, f32 to d_out; 256 blocks = 1 round
  POff pf = {};
  pf.bias[0] = bfc;
  gemm_nt<true,true,false,false><<<dim3(16, 16, 1), 512, 0, stream>>>(
      Ob, wfb, (char*)out, pf, 2048, 2048, 2048, 2048);
}